// Round 4
// baseline (275.785 us; speedup 1.0000x reference)
//
#include <hip/hip_runtime.h>
#include <hip/hip_bf16.h>

// diag(triggers * mask) for N=8192: 8192x8192 fp32 output, zeros off-diag.
// Harness poisons d_out (0xAA) inside the timed iteration -> we must write
// all 256 MiB of zeros per call. Write roofline for OUR part: 256 MiB at
// ~6.6 TB/s (rocclr fill's measured rate) ~= 40 us. The ~201 us of harness
// re-poison (1 GiB ws fill @161 us + out poison) is untouchable.
//
// R2 lesson: 65,536 one-store-per-thread blocks lose ~15-20 us to workgroup
// churn vs a grid-stride streaming loop. R3 lesson: nontemporal builtin needs
// a NATIVE vector type (ext_vector_type), not HIP's float4 class.
// Design: 2048 blocks x 256 threads (8 blocks/CU, full occupancy), 32
// nontemporal 16 B stores per thread, diagonal injected in-register on the
// 1-in-2048 vectors that contain it -> single dispatch, no ordering race.

#define N 8192
#define VEC_COUNT ((size_t)N * N / 4)   // 16,777,216 float4 stores
#define BLOCKS 2048
#define TPB 256

typedef float vfloat4 __attribute__((ext_vector_type(4)));  // native vector

__global__ __launch_bounds__(TPB) void
fill_diag_kernel(const float* __restrict__ triggers,
                 const int* __restrict__ mask,
                 vfloat4* __restrict__ out) {
    const size_t stride = (size_t)BLOCKS * TPB;            // 524,288 threads
    size_t v = (size_t)blockIdx.x * TPB + threadIdx.x;     // float4 index
    const vfloat4 z = (vfloat4)(0.f, 0.f, 0.f, 0.f);
    #pragma unroll 4
    for (; v < VEC_COUNT; v += stride) {                   // 32 iterations
        size_t f = v << 2;                    // flat elem index (4-aligned)
        unsigned r = (unsigned)(f >> 13);     // row
        unsigned d = r - (unsigned)(f & (N - 1));  // diag here iff d < 4
        if (d < 4u) {                         // rare: 1 vector in 2048
            vfloat4 w = z;
            w[d] = triggers[r] * (float)mask[r];
            __builtin_nontemporal_store(w, &out[v]);
        } else {
            __builtin_nontemporal_store(z, &out[v]);
        }
    }
}

extern "C" void kernel_launch(void* const* d_in, const int* in_sizes, int n_in,
                              void* d_out, int out_size, void* d_ws, size_t ws_size,
                              hipStream_t stream) {
    const float* triggers = (const float*)d_in[0];
    const int*   mask     = (const int*)d_in[1];
    vfloat4*     out      = (vfloat4*)d_out;

    fill_diag_kernel<<<BLOCKS, TPB, 0, stream>>>(triggers, mask, out);
}

// Round 5
// 252.512 us; speedup vs baseline: 1.0922x; 1.0922x over previous
//
#include <hip/hip_runtime.h>
#include <hip/hip_bf16.h>

// diag(triggers * mask) for N=8192: 8192x8192 fp32, zeros off-diagonal.
// Harness re-poisons d_out (0xAA) inside the timed iteration -> must write
// all 256 MiB of zeros every call. Pure HBM-write-bound.
//
// Measured across R1-R4: rocclr's fillBufferAligned saturates write BW
// (1 GiB in ~161 us = 6.67 TB/s at only 10% occupancy); every hand-rolled
// fill variant (65k one-store blocks R2, grid-stride+nontemporal R4) lost
// 15-25 us to it. So: hipMemsetAsync for the zero-fill (capture-safe,
// runtime's tuned fill) + one tiny dispatch for the 8192 diagonal elements.
// Controllable cost ~44 us vs 40.2 us write-roofline floor; the remaining
// ~207 us of the timed iteration is the harness's own 0xAA poison fills.

#define N 8192

__global__ void diag_write_kernel(const float* __restrict__ triggers,
                                  const int* __restrict__ mask,
                                  float* __restrict__ out) {
    int i = blockIdx.x * blockDim.x + threadIdx.x;
    if (i < N) {
        size_t idx = (size_t)i * (size_t)(N + 1);  // row i, col i
        out[idx] = triggers[i] * (float)mask[i];
    }
}

extern "C" void kernel_launch(void* const* d_in, const int* in_sizes, int n_in,
                              void* d_out, int out_size, void* d_ws, size_t ws_size,
                              hipStream_t stream) {
    const float* triggers = (const float*)d_in[0];
    const int*   mask     = (const int*)d_in[1];
    float*       out      = (float*)d_out;

    // Zero all 256 MiB (poisoned to 0xAA before each timed call).
    hipMemsetAsync(out, 0, (size_t)N * (size_t)N * sizeof(float), stream);

    // Then write the 8192 diagonal elements.
    diag_write_kernel<<<(N + 255) / 256, 256, 0, stream>>>(triggers, mask, out);
}